// Round 14
// baseline (155.599 us; speedup 1.0000x reference)
//
#include <hip/hip_runtime.h>

// Depthwise 7x7 true-convolution (flipped kernel, SAME zero pad) + mish,
// via MFMA (v_mfma_f32_16x16x32_f16) with banded-Toeplitz weight matrices.
// Round-14: BARRIER-FREE wave-private pipeline.
//  - 8192 waves; each wave independently processes 8 tiles of 16x64 outputs
//    (2 row-bands x 4 col-strips of one plane).
//  - wave-private double-buffered LDS A-tile (22 rows x 88 halfs x 2), so
//    staging needs only wave-local lgkmcnt waits -- NO __syncthreads in the
//    main loop (one at init for the block-shared B matrices). No vmcnt(0)
//    store drains: stores retire asynchronously.
//  - T14 split kept from round-13: raw loads issued before compute,
//    vmcnt-wait + cvt + ds_write after (sched_barrier(0) fences).
//
// Math per 16x16 output subtile, kernel row p:
//   C[i,j] += A_p[i,:] x B_p[:,j],  A_p[i,k] = Xf16[r0+i+p-3, c0-8+16t4+k],
//   B_p[k,j] = W'[p][k-j-5] (banded), W'[p][q] = kern[6-p][6-q].
// MFMA C layout (m89): col = lane&15, row = (lane>>4)*4 + reg.

#define HW 256
#define PITCH 88           // halfs per LDS input row
#define WROWS 22           // 16 + 6 halo rows per wave tile
#define TPW 8              // tiles per wave

typedef _Float16 f16x8 __attribute__((ext_vector_type(8)));
typedef float    f32x4 __attribute__((ext_vector_type(4)));
typedef __fp16   h2    __attribute__((ext_vector_type(2)));
union U32H2 { unsigned u; h2 h; };
union BFU   { uint4 u; f16x8 h; };

__device__ __forceinline__ float mish_f(float y) {
    float t = __expf(y);            // inf-safe: d -> inf -> 2/d -> 0 -> y*1
    float u = 1.0f + t;
    float d = __fmaf_rn(u, u, 1.0f);
    return y * (1.0f - __fdividef(2.0f, d));
}

__global__ __launch_bounds__(256)
__attribute__((amdgpu_waves_per_eu(3, 4)))
void dwconv7_mish_mfma4(const float* __restrict__ x,
                        const float* __restrict__ kern,
                        float* __restrict__ out) {
    // 4 waves x 2 buffers x 1936 halfs = 30,976 B + 7,168 B = 38,144 B
    __shared__ __align__(16) _Float16 lds_in[4][2][WROWS * PITCH];
    __shared__ __align__(16) unsigned lds_B[7 * 256];

    const int tid  = threadIdx.x;
    const int lane = tid & 63;
    const int w    = tid >> 6;
    const int gw   = (blockIdx.x << 2) + w;   // global wave id, 8192 total
    const int plane = gw >> 3;                // 0..1023
    const int ws    = gw & 7;                 // wave slot: row-bands 2ws, 2ws+1

    const float* __restrict__ xp = x + (size_t)plane * (HW * HW);
    float* __restrict__ op = out + (size_t)plane * (HW * HW);

    // Flipped kernel in SGPRs: kf[p*7+q] = kern[6-p][6-q]
    float kf[49];
    #pragma unroll
    for (int i = 0; i < 49; ++i) {
        int p = i / 7, q = i - p * 7;
        kf[i] = __int_as_float(__builtin_amdgcn_readfirstlane(
                    __float_as_int(kern[(6 - p) * 7 + (6 - q)])));
    }

    // Banded-Toeplitz B_p[16][32] f16, word idx = p*256 + j*16 + k/2.
    {
        const int j  = tid >> 4;
        const int kw = tid & 15;
        #pragma unroll
        for (int p = 0; p < 7; ++p) {
            const int d0 = 2 * kw - j - 5;
            const int d1 = d0 + 1;
            float v0 = 0.f, v1 = 0.f;
            #pragma unroll
            for (int q = 0; q < 7; ++q) {
                v0 = (d0 == q) ? kf[p * 7 + q] : v0;
                v1 = (d1 == q) ? kf[p * 7 + q] : v1;
            }
            U32H2 u; u.h = __builtin_amdgcn_cvt_pkrtz(v0, v1);
            lds_B[p * 256 + tid] = u.u;
        }
    }
    __syncthreads();   // the ONLY barrier (B is block-shared, read-only after)

    const int lrow = lane & 15;
    const int lk   = lane >> 4;

    // B fragments hoisted: B[k=8lk+e, j=lrow], contiguous 16 B per lane.
    f16x8 bfrag[7];
    #pragma unroll
    for (int p = 0; p < 7; ++p) {
        BFU bu;
        bu.u = ((const uint4*)lds_B)[(p << 6) + (lrow << 2) + lk];
        bfrag[p] = bu.h;
    }

    // Wave-private staging decomposition: 440 float4 granules per tile
    // (22 rows x 20), granule idx = lane + 64*it; it=6 only lanes < 56.
    int ro_[7], co_[7], lo_[7];
    #pragma unroll
    for (int it = 0; it < 7; ++it) {
        int idx = lane + (it << 6);
        int r = idx / 20, g = idx - 20 * r;
        ro_[it] = r - 3;
        co_[it] = 4 * g - 8;
        lo_[it] = r * 22 + g;                 // uint2 slot within buffer
    }

    // Prologue: stage tile 0 (r0 = 32*ws, c0 = 0) into buf0, direct cvt.
    {
        const int r0 = ws << 5;
        #pragma unroll
        for (int it = 0; it < 7; ++it) {
            if (it < 6 || lane < 56) {
                int gr = r0 + ro_[it], gc = co_[it];
                float4 f = make_float4(0.f, 0.f, 0.f, 0.f);
                if ((unsigned)gr < (unsigned)HW && (unsigned)gc <= (unsigned)(HW - 4))
                    f = *(const float4*)(xp + (gr << 8) + gc);
                U32H2 a, b;
                a.h = __builtin_amdgcn_cvt_pkrtz(f.x, f.y);
                b.h = __builtin_amdgcn_cvt_pkrtz(f.z, f.w);
                ((uint2*)lds_in[w][0])[lo_[it]] = make_uint2(a.u, b.u);
            }
        }
    }

    float4 rf[7];

    #pragma unroll 1
    for (int t = 0; t < TPW; ++t) {
        const int r0 = ((ws << 1) + (t >> 2)) << 4;
        const int c0 = (t & 3) << 6;

        // ---- step 1: issue next tile's RAW loads (no consumption) ----
        if (t + 1 < TPW) {
            const int r2 = ((ws << 1) + ((t + 1) >> 2)) << 4;
            const int c2 = ((t + 1) & 3) << 6;
            #pragma unroll
            for (int it = 0; it < 7; ++it) {
                if (it < 6 || lane < 56) {
                    int gr = r2 + ro_[it], gc = c2 + co_[it];
                    rf[it] = make_float4(0.f, 0.f, 0.f, 0.f);
                    if ((unsigned)gr < (unsigned)HW && (unsigned)gc <= (unsigned)(HW - 4))
                        rf[it] = *(const float4*)(xp + (gr << 8) + gc);
                }
            }
        }
        __builtin_amdgcn_sched_barrier(0);

        // ---- step 2: compute current tile from wave-private buffer ----
        const _Float16* bufp = lds_in[w][t & 1];
        #pragma unroll
        for (int t4 = 0; t4 < 4; ++t4) {
            f32x4 acc = {0.f, 0.f, 0.f, 0.f};
            #pragma unroll
            for (int p = 0; p < 7; ++p) {
                f16x8 a = *(const f16x8*)(bufp +
                            (lrow + p) * PITCH + 16 * t4 + 8 * lk);
                acc = __builtin_amdgcn_mfma_f32_16x16x32_f16(a, bfrag[p], acc,
                                                             0, 0, 0);
            }
            const int col = c0 + 16 * t4 + lrow;
            const int rb  = r0 + (lk << 2);
            op[(rb + 0) * HW + col] = mish_f(acc[0]);
            op[(rb + 1) * HW + col] = mish_f(acc[1]);
            op[(rb + 2) * HW + col] = mish_f(acc[2]);
            op[(rb + 3) * HW + col] = mish_f(acc[3]);
        }
        __builtin_amdgcn_sched_barrier(0);

        // ---- step 3: consume loads (vmcnt wait lands here), cvt, ds_write
        //      into the other wave-private buffer; next iteration's ds_read
        //      gets a wave-local lgkmcnt wait from the compiler. ----
        if (t + 1 < TPW) {
            _Float16* dstb = lds_in[w][(t + 1) & 1];
            #pragma unroll
            for (int it = 0; it < 7; ++it) {
                if (it < 6 || lane < 56) {
                    U32H2 a, b;
                    a.h = __builtin_amdgcn_cvt_pkrtz(rf[it].x, rf[it].y);
                    b.h = __builtin_amdgcn_cvt_pkrtz(rf[it].z, rf[it].w);
                    ((uint2*)dstb)[lo_[it]] = make_uint2(a.u, b.u);
                }
            }
        }
    }
}

extern "C" void kernel_launch(void* const* d_in, const int* in_sizes, int n_in,
                              void* d_out, int out_size, void* d_ws, size_t ws_size,
                              hipStream_t stream) {
    const float* x = (const float*)d_in[0];
    const float* k = (const float*)d_in[1];
    float* out = (float*)d_out;

    dim3 grid(2048, 1, 1);   // 8192 waves = 8 per plane
    dim3 block(256);
    dwconv7_mish_mfma4<<<grid, block, 0, stream>>>(x, k, out);
}

// Round 15
// 132.688 us; speedup vs baseline: 1.1727x; 1.1727x over previous
//
#include <hip/hip_runtime.h>

// Depthwise 7x7 true-convolution (flipped kernel, SAME zero pad) + mish,
// via MFMA (v_mfma_f32_16x16x32_f16) with banded-Toeplitz weight matrices.
// Round-15 = round-13 (best, 132.6us) with ONE change: the per-tile
// __syncthreads (which drains vmcnt(0) -> waits for all in-flight global
// STORES, 8x per block) is replaced by a drain-free barrier:
//     s_waitcnt lgkmcnt(0)   ; LDS visibility only
//     s_barrier
// Stores retire asynchronously across tiles; tile t+1's loads were already
// vmcnt-consumed in step 3. Ring safety: the single barrier per tile still
// orders every wave's step-2 read of buf[t&1] before any wave's step-3
// write of buf[t&1] (next occurrence is 2 tiles later), and lgkmcnt(0)
// before s_barrier makes each wave's ds_writes visible to all. Rule #18:
// sched_barrier(0) after the asm keeps the compiler from hoisting next
// iteration's ops above it.
//
// Math per 16x16 output subtile, kernel row p:
//   C[i,j] += A_p[i,:] x B_p[:,j],  A_p[i,k] = Xf16[r0+i+p-3, c0-8+16t+k],
//   B_p[k,j] = W'[p][k-j-5] (banded), W'[p][q] = kern[6-p][6-q].
// MFMA C layout (m89): col = lane&15, row = (lane>>4)*4 + reg.

#define HW 256
#define PITCH 88           // halfs per LDS input row
#define LROWS 70           // 64 + 6 halo
#define NSTG 1400          // 70 rows * 20 float4 granules
#define TPB 8              // tiles per block (half a plane)

typedef _Float16 f16x8 __attribute__((ext_vector_type(8)));
typedef float    f32x4 __attribute__((ext_vector_type(4)));
typedef __fp16   h2    __attribute__((ext_vector_type(2)));
union U32H2 { unsigned u; h2 h; };
union BFU   { uint4 u; f16x8 h; };

__device__ __forceinline__ float mish_f(float y) {
    float t = __expf(y);            // inf-safe: d -> inf -> 2/d -> 0 -> y*1
    float u = 1.0f + t;
    float d = __fmaf_rn(u, u, 1.0f);
    return y * (1.0f - __fdividef(2.0f, d));
}

__global__ __launch_bounds__(256)
__attribute__((amdgpu_waves_per_eu(3, 5)))
void dwconv7_mish_mfma5(const float* __restrict__ x,
                        const float* __restrict__ kern,
                        float* __restrict__ out) {
    __shared__ __align__(16) _Float16 lds_in[2][LROWS * PITCH]; // 2 x 12320 B
    __shared__ __align__(16) unsigned lds_B[7 * 256];           // 7168 B

    const int tid = threadIdx.x;
    const int bid = blockIdx.x;
    const int plane = bid >> 1;          // 2 blocks per plane
    const int sbase = (bid & 1) << 3;    // tile slot: c0=(s&3)*64, r0=(s>>2)*64

    const float* __restrict__ xp = x + (size_t)plane * (HW * HW);
    float* __restrict__ op = out + (size_t)plane * (HW * HW);

    // Flipped kernel in SGPRs: kf[p*7+q] = kern[6-p][6-q]
    float kf[49];
    #pragma unroll
    for (int i = 0; i < 49; ++i) {
        int p = i / 7, q = i - p * 7;
        kf[i] = __int_as_float(__builtin_amdgcn_readfirstlane(
                    __float_as_int(kern[(6 - p) * 7 + (6 - q)])));
    }

    // Banded-Toeplitz B_p[16][32] f16, word idx = p*256 + j*16 + k/2.
    {
        const int j  = tid >> 4;
        const int kw = tid & 15;
        #pragma unroll
        for (int p = 0; p < 7; ++p) {
            const int d0 = 2 * kw - j - 5;
            const int d1 = d0 + 1;
            float v0 = 0.f, v1 = 0.f;
            #pragma unroll
            for (int q = 0; q < 7; ++q) {
                v0 = (d0 == q) ? kf[p * 7 + q] : v0;
                v1 = (d1 == q) ? kf[p * 7 + q] : v1;
            }
            U32H2 u; u.h = __builtin_amdgcn_cvt_pkrtz(v0, v1);
            lds_B[p * 256 + tid] = u.u;
        }
    }

    // Per-thread staging decomposition: idx = tid+256*it -> r=idx/20, g=idx%20.
    int ro_[6], co_[6], lo_[6];
    #pragma unroll
    for (int it = 0; it < 6; ++it) {
        int idx = tid + it * 256;
        int r = idx / 20, g = idx - 20 * r;
        ro_[it] = r - 3;
        co_[it] = 4 * g - 8;
        lo_[it] = r * 22 + g;
    }

    // Prologue: stage tile sbase into buf0 (immediate cvt is fine here).
    {
        const int c0 = (sbase & 3) << 6, r0 = (sbase >> 2) << 6;
        #pragma unroll
        for (int it = 0; it < 6; ++it) {
            if (it < 5 || tid < NSTG - 1280) {
                int gr = r0 + ro_[it], gc = c0 + co_[it];
                float4 f = make_float4(0.f, 0.f, 0.f, 0.f);
                if ((unsigned)gr < (unsigned)HW && (unsigned)gc <= (unsigned)(HW - 4))
                    f = *(const float4*)(xp + (gr << 8) + gc);
                U32H2 a, b;
                a.h = __builtin_amdgcn_cvt_pkrtz(f.x, f.y);
                b.h = __builtin_amdgcn_cvt_pkrtz(f.z, f.w);
                ((uint2*)lds_in[0])[lo_[it]] = make_uint2(a.u, b.u);
            }
        }
    }
    __syncthreads();   // full barrier once (B + buf0 ready)

    const int lane = tid & 63;
    const int w    = tid >> 6;           // wave: tile rows 16w..16w+15
    const int lrow = lane & 15;
    const int lk   = lane >> 4;

    // B fragments hoisted: B[k=lk*8+e, j=lrow], contiguous 16 B per lane.
    f16x8 bfrag[7];
    #pragma unroll
    for (int p = 0; p < 7; ++p) {
        BFU bu;
        bu.u = ((const uint4*)lds_B)[p * 64 + lrow * 4 + lk];
        bfrag[p] = bu.h;
    }

    float4 rf[6];

    #pragma unroll 1
    for (int t = 0; t < TPB; ++t) {
        const int s  = sbase + t;
        const int c0 = (s & 3) << 6, r0 = (s >> 2) << 6;

        // ---- step 1: issue next tile's RAW loads (no consumption) ----
        if (t + 1 < TPB) {
            const int s2 = sbase + t + 1;
            const int c2 = (s2 & 3) << 6, r2 = (s2 >> 2) << 6;
            #pragma unroll
            for (int it = 0; it < 6; ++it) {
                if (it < 5 || tid < NSTG - 1280) {
                    int gr = r2 + ro_[it], gc = c2 + co_[it];
                    rf[it] = make_float4(0.f, 0.f, 0.f, 0.f);
                    if ((unsigned)gr < (unsigned)HW && (unsigned)gc <= (unsigned)(HW - 4))
                        rf[it] = *(const float4*)(xp + (gr << 8) + gc);
                }
            }
        }
        __builtin_amdgcn_sched_barrier(0);

        // ---- step 2: compute current tile from lds_in[t&1] ----
        const _Float16* bufp = lds_in[t & 1];
        #pragma unroll
        for (int t4 = 0; t4 < 4; ++t4) {
            f32x4 acc = {0.f, 0.f, 0.f, 0.f};
            #pragma unroll
            for (int p = 0; p < 7; ++p) {
                f16x8 a = *(const f16x8*)(bufp +
                            (16 * w + lrow + p) * PITCH + 16 * t4 + 8 * lk);
                acc = __builtin_amdgcn_mfma_f32_16x16x32_f16(a, bfrag[p], acc,
                                                             0, 0, 0);
            }
            const int col   = c0 + 16 * t4 + lrow;
            const int rbase = r0 + 16 * w + 4 * lk;
            op[(rbase + 0) * HW + col] = mish_f(acc[0]);
            op[(rbase + 1) * HW + col] = mish_f(acc[1]);
            op[(rbase + 2) * HW + col] = mish_f(acc[2]);
            op[(rbase + 3) * HW + col] = mish_f(acc[3]);
        }
        __builtin_amdgcn_sched_barrier(0);

        // ---- step 3: consume loads (vmcnt wait lands HERE), cvt, ds_write ----
        if (t + 1 < TPB) {
            #pragma unroll
            for (int it = 0; it < 6; ++it) {
                if (it < 5 || tid < NSTG - 1280) {
                    U32H2 a, b;
                    a.h = __builtin_amdgcn_cvt_pkrtz(rf[it].x, rf[it].y);
                    b.h = __builtin_amdgcn_cvt_pkrtz(rf[it].z, rf[it].w);
                    ((uint2*)lds_in[(t + 1) & 1])[lo_[it]] = make_uint2(a.u, b.u);
                }
            }
        }

        // ---- step 4: drain-free barrier: LDS visibility only, no vmcnt(0)
        //      (global stores keep retiring asynchronously across tiles) ----
        asm volatile("s_waitcnt lgkmcnt(0)\n\ts_barrier" ::: "memory");
        __builtin_amdgcn_sched_barrier(0);
    }
}

extern "C" void kernel_launch(void* const* d_in, const int* in_sizes, int n_in,
                              void* d_out, int out_size, void* d_ws, size_t ws_size,
                              hipStream_t stream) {
    const float* x = (const float*)d_in[0];
    const float* k = (const float*)d_in[1];
    float* out = (float*)d_out;

    dim3 grid(2 * 16 * 64, 1, 1);   // 2048 blocks: 2 per plane
    dim3 block(256);
    dwconv7_mish_mfma5<<<grid, block, 0, stream>>>(x, k, out);
}

// Round 16
// 128.103 us; speedup vs baseline: 1.2146x; 1.0358x over previous
//
#include <hip/hip_runtime.h>

// Depthwise 7x7 true-convolution (flipped kernel, SAME zero pad) + mish,
// via MFMA (v_mfma_f32_16x16x32_f16) with banded-Toeplitz weight matrices.
// Round-16 = round-15 with the LDS footprint cut 31.8 -> 22.4 KB to raise
// occupancy (R15 A/B falsified the barrier-drain theory; all pipes <=50%
// busy + near-ideal traffic => latency-bound, need more resident waves):
//  - PITCH 88 -> 80 halfs (still conflict-free: A-read start-bank
//    8*(lrow&3)+4*lk -> 8 groups x 8 lanes x 4 words = uniform 8 words/bank,
//    the ds_read_b128 minimum; staging writes lane-linear = 2-way free).
//  - B-matrix scratch aliased into A-buffer 1 (read into bfrag registers
//    before buf1's first staging write; 2 prologue barriers order it).
//  - waves_per_eu(4,7): min gentle (R13 used 56 VGPR naturally), max 7
//    allows 7 blocks/CU at 22.4 KB.
//
// Math per 16x16 output subtile, kernel row p:
//   C[i,j] += A_p[i,:] x B_p[:,j],  A_p[i,k] = Xf16[r0+i+p-3, c0-8+16t+k],
//   B_p[k,j] = W'[p][k-j-5] (banded), W'[p][q] = kern[6-p][6-q].
// MFMA C layout (m89): col = lane&15, row = (lane>>4)*4 + reg.

#define HW 256
#define PITCH 80           // halfs per LDS input row (20 float4 granules)
#define LROWS 70           // 64 + 6 halo
#define NSTG 1400          // 70 rows * 20 granules
#define TPB 8              // tiles per block (half a plane)

typedef _Float16 f16x8 __attribute__((ext_vector_type(8)));
typedef float    f32x4 __attribute__((ext_vector_type(4)));
typedef __fp16   h2    __attribute__((ext_vector_type(2)));
union U32H2 { unsigned u; h2 h; };
union BFU   { uint4 u; f16x8 h; };

__device__ __forceinline__ float mish_f(float y) {
    float t = __expf(y);            // inf-safe: d -> inf -> 2/d -> 0 -> y*1
    float u = 1.0f + t;
    float d = __fmaf_rn(u, u, 1.0f);
    return y * (1.0f - __fdividef(2.0f, d));
}

__global__ __launch_bounds__(256)
__attribute__((amdgpu_waves_per_eu(4, 7)))
void dwconv7_mish_mfma6(const float* __restrict__ x,
                        const float* __restrict__ kern,
                        float* __restrict__ out) {
    // 2 x 70 x 80 halfs = 22,400 B total; B (7,168 B) aliases buffer 1.
    __shared__ __align__(16) _Float16 lds_in[2][LROWS * PITCH];

    const int tid = threadIdx.x;
    const int bid = blockIdx.x;
    const int plane = bid >> 1;          // 2 blocks per plane
    const int sbase = (bid & 1) << 3;    // tile slot: c0=(s&3)*64, r0=(s>>2)*64

    const float* __restrict__ xp = x + (size_t)plane * (HW * HW);
    float* __restrict__ op = out + (size_t)plane * (HW * HW);

    unsigned* lds_B = (unsigned*)lds_in[1];   // scratch alias, 7*256 words

    // Flipped kernel in SGPRs: kf[p*7+q] = kern[6-p][6-q]
    float kf[49];
    #pragma unroll
    for (int i = 0; i < 49; ++i) {
        int p = i / 7, q = i - p * 7;
        kf[i] = __int_as_float(__builtin_amdgcn_readfirstlane(
                    __float_as_int(kern[(6 - p) * 7 + (6 - q)])));
    }

    // Banded-Toeplitz B_p[16][32] f16, word idx = p*256 + j*16 + k/2.
    {
        const int j  = tid >> 4;
        const int kw = tid & 15;
        #pragma unroll
        for (int p = 0; p < 7; ++p) {
            const int d0 = 2 * kw - j - 5;
            const int d1 = d0 + 1;
            float v0 = 0.f, v1 = 0.f;
            #pragma unroll
            for (int q = 0; q < 7; ++q) {
                v0 = (d0 == q) ? kf[p * 7 + q] : v0;
                v1 = (d1 == q) ? kf[p * 7 + q] : v1;
            }
            U32H2 u; u.h = __builtin_amdgcn_cvt_pkrtz(v0, v1);
            lds_B[p * 256 + tid] = u.u;
        }
    }

    // Per-thread staging decomposition: idx = tid+256*it -> r=idx/20, g=idx%20;
    // LDS uint2 slot is idx itself (PITCH==20 granules, no pad).
    int ro_[6], co_[6];
    #pragma unroll
    for (int it = 0; it < 6; ++it) {
        int idx = tid + it * 256;
        int r = idx / 20, g = idx - 20 * r;
        ro_[it] = r - 3;
        co_[it] = 4 * g - 8;
    }

    // Prologue: stage tile sbase into buf0 (immediate cvt is fine here).
    {
        const int c0 = (sbase & 3) << 6, r0 = (sbase >> 2) << 6;
        #pragma unroll
        for (int it = 0; it < 6; ++it) {
            if (it < 5 || tid < NSTG - 1280) {
                int gr = r0 + ro_[it], gc = c0 + co_[it];
                float4 f = make_float4(0.f, 0.f, 0.f, 0.f);
                if ((unsigned)gr < (unsigned)HW && (unsigned)gc <= (unsigned)(HW - 4))
                    f = *(const float4*)(xp + (gr << 8) + gc);
                U32H2 a, b;
                a.h = __builtin_amdgcn_cvt_pkrtz(f.x, f.y);
                b.h = __builtin_amdgcn_cvt_pkrtz(f.z, f.w);
                ((uint2*)lds_in[0])[tid + it * 256] = make_uint2(a.u, b.u);
            }
        }
    }
    __syncthreads();   // B + buf0 visible

    const int lane = tid & 63;
    const int w    = tid >> 6;           // wave: tile rows 16w..16w+15
    const int lrow = lane & 15;
    const int lk   = lane >> 4;

    // B fragments hoisted: B[k=lk*8+e, j=lrow], contiguous 16 B per lane.
    f16x8 bfrag[7];
    #pragma unroll
    for (int p = 0; p < 7; ++p) {
        BFU bu;
        bu.u = ((const uint4*)lds_B)[p * 64 + lrow * 4 + lk];
        bfrag[p] = bu.h;
    }
    __syncthreads();   // all bfrag reads done before buf1 is overwritten

    float4 rf[6];

    #pragma unroll 1
    for (int t = 0; t < TPB; ++t) {
        const int s  = sbase + t;
        const int c0 = (s & 3) << 6, r0 = (s >> 2) << 6;

        // ---- step 1: issue next tile's RAW loads (no consumption) ----
        if (t + 1 < TPB) {
            const int s2 = sbase + t + 1;
            const int c2 = (s2 & 3) << 6, r2 = (s2 >> 2) << 6;
            #pragma unroll
            for (int it = 0; it < 6; ++it) {
                if (it < 5 || tid < NSTG - 1280) {
                    int gr = r2 + ro_[it], gc = c2 + co_[it];
                    rf[it] = make_float4(0.f, 0.f, 0.f, 0.f);
                    if ((unsigned)gr < (unsigned)HW && (unsigned)gc <= (unsigned)(HW - 4))
                        rf[it] = *(const float4*)(xp + (gr << 8) + gc);
                }
            }
        }
        __builtin_amdgcn_sched_barrier(0);

        // ---- step 2: compute current tile from lds_in[t&1] ----
        const _Float16* bufp = lds_in[t & 1];
        #pragma unroll
        for (int t4 = 0; t4 < 4; ++t4) {
            f32x4 acc = {0.f, 0.f, 0.f, 0.f};
            #pragma unroll
            for (int p = 0; p < 7; ++p) {
                f16x8 a = *(const f16x8*)(bufp +
                            (16 * w + lrow + p) * PITCH + 16 * t4 + 8 * lk);
                acc = __builtin_amdgcn_mfma_f32_16x16x32_f16(a, bfrag[p], acc,
                                                             0, 0, 0);
            }
            const int col   = c0 + 16 * t4 + lrow;
            const int rbase = r0 + 16 * w + 4 * lk;
            op[(rbase + 0) * HW + col] = mish_f(acc[0]);
            op[(rbase + 1) * HW + col] = mish_f(acc[1]);
            op[(rbase + 2) * HW + col] = mish_f(acc[2]);
            op[(rbase + 3) * HW + col] = mish_f(acc[3]);
        }
        __builtin_amdgcn_sched_barrier(0);

        // ---- step 3: consume loads (vmcnt wait lands HERE), cvt, ds_write ----
        if (t + 1 < TPB) {
            #pragma unroll
            for (int it = 0; it < 6; ++it) {
                if (it < 5 || tid < NSTG - 1280) {
                    U32H2 a, b;
                    a.h = __builtin_amdgcn_cvt_pkrtz(rf[it].x, rf[it].y);
                    b.h = __builtin_amdgcn_cvt_pkrtz(rf[it].z, rf[it].w);
                    ((uint2*)lds_in[(t + 1) & 1])[tid + it * 256] = make_uint2(a.u, b.u);
                }
            }
        }

        // ---- step 4: drain-free barrier (LDS visibility only) ----
        asm volatile("s_waitcnt lgkmcnt(0)\n\ts_barrier" ::: "memory");
        __builtin_amdgcn_sched_barrier(0);
    }
}

extern "C" void kernel_launch(void* const* d_in, const int* in_sizes, int n_in,
                              void* d_out, int out_size, void* d_ws, size_t ws_size,
                              hipStream_t stream) {
    const float* x = (const float*)d_in[0];
    const float* k = (const float*)d_in[1];
    float* out = (float*)d_out;

    dim3 grid(2 * 16 * 64, 1, 1);   // 2048 blocks: 2 per plane
    dim3 block(256);
    dwconv7_mish_mfma6<<<grid, block, 0, stream>>>(x, k, out);
}